// Round 5
// baseline (218.331 us; speedup 1.0000x reference)
//
#include <hip/hip_runtime.h>

// B=16, T=256, C=6, E=512, H=8, hd=64.
// Inputs fp32 (reference dtype); OUTPUT fp32 (reference dtype) — round-4 finding:
// error 1.203 == exact fingerprint of bf16-packed writes read back as fp32.
// Compute in bf16 MFMA (2%-of-max tolerance mode); biases added in fp32.

typedef unsigned short u16;
typedef short bf16x8 __attribute__((ext_vector_type(8)));   // 8 bf16 = 4 VGPRs
typedef float f32x4 __attribute__((ext_vector_type(4)));
typedef u16 u16x4 __attribute__((ext_vector_type(4)));

#define MFMA16(a, b, c) __builtin_amdgcn_mfma_f32_16x16x32_bf16((a), (b), (c), 0, 0, 0)

__device__ __forceinline__ u16 f2b(float f) {
  union { float f; unsigned u; } v; v.f = f;
  unsigned r = v.u + 0x7fffu + ((v.u >> 16) & 1u);   // RNE (finite inputs)
  return (u16)(r >> 16);
}
__device__ __forceinline__ void gl_lds16(const void* g, void* l) {
  __builtin_amdgcn_global_load_lds(
      (const __attribute__((address_space(1))) void*)g,
      (__attribute__((address_space(3))) void*)l, 16, 0, 0);
}

// ---------------------------------------------------------------------------
// fp32 -> bf16 converters
// ---------------------------------------------------------------------------
__global__ void cvt_w(const float* W0, const float* W1, const float* W2,
                      const float* W3, u16* dst) {
  const float* src = (blockIdx.y == 0) ? W0 : (blockIdx.y == 1) ? W1
                   : (blockIdx.y == 2) ? W2 : W3;
  const int idx = (blockIdx.x * 256 + threadIdx.x) * 4;
  f32x4 v = *(const f32x4*)(src + idx);
  u16x4 o; o.x = f2b(v.x); o.y = f2b(v.y); o.z = f2b(v.z); o.w = f2b(v.w);
  *(u16x4*)(dst + (size_t)blockIdx.y * 262144 + idx) = o;
}

__global__ void cvt_x(const float* __restrict__ src, u16* __restrict__ dst) {
  const size_t idx = ((size_t)blockIdx.x * 256 + threadIdx.x) * 4;
  f32x4 v = *(const f32x4*)(src + idx);
  u16x4 o; o.x = f2b(v.x); o.y = f2b(v.y); o.z = f2b(v.z); o.w = f2b(v.w);
  *(u16x4*)(dst + idx) = o;
}

// ---------------------------------------------------------------------------
// BT-GEMM (m97 pattern, bf16, 16 KB LDS): C[m][n] = sum_k A[m][k]*W[n][k] + b[n]
// qkv_mode=1: z selects W/bias, bf16 scatter-store to [b,h,c,t,d] (O).
// qkv_mode=0: fp32 row-major store to OF (the final output).
// ---------------------------------------------------------------------------
__global__ __launch_bounds__(256, 3) void gemm_bt(
    const u16* __restrict__ A,
    const u16* W0, const u16* W1, const u16* W2,
    const float* bs0, const float* bs1, const float* bs2,
    u16* O0, u16* O1, u16* O2,
    float* OF,
    int qkv_mode)
{
  const int z = blockIdx.z;
  const u16* W    = (z == 0) ? W0 : (z == 1) ? W1 : W2;
  const float* bs = (z == 0) ? bs0 : (z == 1) ? bs1 : bs2;
  u16* O          = (z == 0) ? O0 : (z == 1) ? O1 : O2;

  const int m0 = blockIdx.x * 128;
  const int n0 = blockIdx.y * 128;

  __shared__ u16 As[128 * 32];   // 8 KB, 64B rows, chunk swizzle (q + (row>>1)) & 3
  __shared__ u16 Bs[128 * 32];

  const int tid  = threadIdx.x;
  const int lane = tid & 63;
  const int wv   = tid >> 6;
  const int r    = lane & 15;
  const int qd   = lane >> 4;
  const int wm   = (wv & 1) * 64;
  const int wn   = (wv >> 1) * 64;

  f32x4 acc[4][4] = {};

  for (int k0 = 0; k0 < 512; k0 += 32) {
    __syncthreads();
    #pragma unroll
    for (int it = 0; it < 2; ++it) {
      const int flat = (it * 256 + tid) * 16;       // byte offset in 8KB tile
      const int row  = flat >> 6;                   // 64 B per row
      const int swc  = (flat >> 4) & 3;
      const int gc   = (swc - (row >> 1)) & 3;      // un-swizzle for global side
      gl_lds16((const char*)A + (size_t)(m0 + row) * 1024 + k0 * 2 + gc * 16,
               (char*)As + flat);
      gl_lds16((const char*)W + (size_t)(n0 + row) * 1024 + k0 * 2 + gc * 16,
               (char*)Bs + flat);
    }
    __syncthreads();

    bf16x8 af[4], bf[4];
    #pragma unroll
    for (int mt = 0; mt < 4; ++mt) {
      const int row = wm + mt * 16 + r;
      const int sw  = (qd + (row >> 1)) & 3;
      af[mt] = *(const bf16x8*)((const char*)As + row * 64 + sw * 16);
    }
    #pragma unroll
    for (int nt = 0; nt < 4; ++nt) {
      const int row = wn + nt * 16 + r;
      const int sw  = (qd + (row >> 1)) & 3;
      bf[nt] = *(const bf16x8*)((const char*)Bs + row * 64 + sw * 16);
    }
    #pragma unroll
    for (int mt = 0; mt < 4; ++mt)
      #pragma unroll
      for (int nt = 0; nt < 4; ++nt)
        acc[mt][nt] = MFMA16(af[mt], bf[nt], acc[mt][nt]);
  }

  float bv[4];
  #pragma unroll
  for (int nt = 0; nt < 4; ++nt) bv[nt] = bs[n0 + wn + nt * 16 + r];

  if (qkv_mode) {
    #pragma unroll
    for (int mt = 0; mt < 4; ++mt) {
      #pragma unroll
      for (int rr = 0; rr < 4; ++rr) {
        const int m   = m0 + wm + mt * 16 + qd * 4 + rr;   // (b*T+t)*C + c
        const int b   = m / 1536;
        const int rem = m - b * 1536;
        const int t   = rem / 6;
        const int c   = rem - t * 6;
        #pragma unroll
        for (int nt = 0; nt < 4; ++nt) {
          const int f = n0 + wn + nt * 16 + r;             // h*64 + d
          const int h = f >> 6;
          const int d = f & 63;
          const size_t addr = ((((size_t)b * 8 + h) * 6 + c) * 256 + t) * 64 + d;
          O[addr] = f2b(acc[mt][nt][rr] + bv[nt]);
        }
      }
    }
  } else {
    #pragma unroll
    for (int mt = 0; mt < 4; ++mt) {
      #pragma unroll
      for (int rr = 0; rr < 4; ++rr) {
        const int m = m0 + wm + mt * 16 + qd * 4 + rr;
        #pragma unroll
        for (int nt = 0; nt < 4; ++nt) {
          const int f = n0 + wn + nt * 16 + r;
          OF[(size_t)m * 512 + f] = acc[mt][nt][rr] + bv[nt];   // fp32 output
        }
      }
    }
  }
}

// ---------------------------------------------------------------------------
// Causal attention, one block per (b,h,c).  512 threads = 8 waves.
// Wave w owns query tiles {w, 15-w}; keys in 2 super-chunks of 128.
// LDS = 18+17+18 = 53 KB (< 64 KB per-workgroup cap).
// ---------------------------------------------------------------------------
__global__ __launch_bounds__(512, 2) void attn(
    const u16* __restrict__ q_ws, const u16* __restrict__ k_ws,
    const u16* __restrict__ v_ws, u16* __restrict__ y_ws)
{
  const int blk = blockIdx.x;            // (b*8 + h)*6 + c  (b slab-local)
  const int b   = blk / 48;
  const int h   = (blk / 6) % 8;
  const int c   = blk % 6;
  const size_t base = (size_t)blk * 256 * 64;

  __shared__ u16 Ks[128 * 72];           // 18 KB  K super-chunk, padded stride
  __shared__ u16 Vts[64 * 136];          // 17 KB  V^T super-chunk
  __shared__ u16 Ps[8][16 * 72];         // 18 KB  per-wave P tile

  const int tid  = threadIdx.x;
  const int lane = tid & 63;
  const int wv   = tid >> 6;
  const int r    = lane & 15;
  const int qd   = lane >> 4;

  const int tiles[2] = { wv, 15 - wv };

  bf16x8 qf[2][2];
  #pragma unroll
  for (int ti = 0; ti < 2; ++ti)
    #pragma unroll
    for (int kc = 0; kc < 2; ++kc)
      qf[ti][kc] = *(const bf16x8*)(q_ws + base +
                     (size_t)(tiles[ti] * 16 + r) * 64 + kc * 32 + qd * 8);

  f32x4 o_acc[2][4] = {};
  float l_acc[2][4] = {{0.f,0.f,0.f,0.f},{0.f,0.f,0.f,0.f}};

  for (int sc = 0; sc < 2; ++sc) {
    __syncthreads();
    #pragma unroll
    for (int it = 0; it < 2; ++it) {
      const int idx = it * 512 + tid;
      const int row = idx >> 3;
      const int c8  = idx & 7;
      *(bf16x8*)(Ks + row * 72 + c8 * 8) =
          *(const bf16x8*)(k_ws + base + (size_t)(sc * 128 + row) * 64 + c8 * 8);
    }
    {
      const int jl = tid & 127;
      const int d0 = (tid >> 7) * 16;
      #pragma unroll
      for (int dd = 0; dd < 16; dd += 8) {
        bf16x8 vv = *(const bf16x8*)(v_ws + base +
                       (size_t)(sc * 128 + jl) * 64 + d0 + dd);
        #pragma unroll
        for (int e = 0; e < 8; ++e)
          Vts[(d0 + dd + e) * 136 + jl] = ((u16*)&vv)[e];
      }
    }
    __syncthreads();

    #pragma unroll
    for (int ti = 0; ti < 2; ++ti) {
      const int mt  = tiles[ti];
      const int i0  = mt * 16;
      const int nch = (mt >> 2) + 1;
      #pragma unroll
      for (int jcl = 0; jcl < 2; ++jcl) {
        const int jc = sc * 2 + jcl;
        if (jc >= nch) continue;            // wave-uniform skip
        const int j0l = jcl * 64;
        const int j0g = sc * 128 + j0l;

        f32x4 s[4] = {};
        #pragma unroll
        for (int nt = 0; nt < 4; ++nt)
          #pragma unroll
          for (int kc = 0; kc < 2; ++kc) {
            bf16x8 kf = *(const bf16x8*)(Ks + (j0l + nt * 16 + r) * 72 +
                                         kc * 32 + qd * 8);
            s[nt] = MFMA16(qf[ti][kc], kf, s[nt]);
          }

        #pragma unroll
        for (int nt = 0; nt < 4; ++nt)
          #pragma unroll
          for (int rr = 0; rr < 4; ++rr) {
            const int i = i0 + qd * 4 + rr;
            const int j = j0g + nt * 16 + r;
            float p = __builtin_exp2f(fminf(s[nt][rr], 500.f) *
                                      0.1803368801111244f);  // *(1/8)*log2(e)
            if (j > i) p = 0.f;
            l_acc[ti][rr] += p;
            Ps[wv][(qd * 4 + rr) * 72 + nt * 16 + r] = f2b(p);
          }
        asm volatile("s_waitcnt lgkmcnt(0)" ::: "memory");

        bf16x8 pf[2];
        #pragma unroll
        for (int kc = 0; kc < 2; ++kc)
          pf[kc] = *(const bf16x8*)(Ps[wv] + r * 72 + kc * 32 + qd * 8);
        #pragma unroll
        for (int ntd = 0; ntd < 4; ++ntd)
          #pragma unroll
          for (int kc = 0; kc < 2; ++kc) {
            bf16x8 vf = *(const bf16x8*)(Vts + (ntd * 16 + r) * 136 +
                                         j0l + kc * 32 + qd * 8);
            o_acc[ti][ntd] = MFMA16(pf[kc], vf, o_acc[ti][ntd]);
          }
      }
    }
  }

  const size_t obase = ((size_t)b * 256) * 3072 + h * 384 + c * 64;
  #pragma unroll
  for (int ti = 0; ti < 2; ++ti) {
    const int i0 = tiles[ti] * 16;
    float linv[4];
    #pragma unroll
    for (int rr = 0; rr < 4; ++rr) {
      float sum = l_acc[ti][rr];
      sum += __shfl_xor(sum, 1, 16);
      sum += __shfl_xor(sum, 2, 16);
      sum += __shfl_xor(sum, 4, 16);
      sum += __shfl_xor(sum, 8, 16);
      linv[rr] = 1.f / sum;
    }
    #pragma unroll
    for (int ntd = 0; ntd < 4; ++ntd)
      #pragma unroll
      for (int rr = 0; rr < 4; ++rr) {
        const int t = i0 + qd * 4 + rr;
        const int d = ntd * 16 + r;
        y_ws[obase + (size_t)t * 3072 + d] = f2b(o_acc[ti][ntd][rr] * linv[rr]);
      }
  }
}

// ---------------------------------------------------------------------------
extern "C" void kernel_launch(void* const* d_in, const int* in_sizes, int n_in,
                              void* d_out, int out_size, void* d_ws, size_t ws_size,
                              hipStream_t stream) {
  const float* x  = (const float*)d_in[0];
  const float* Wq = (const float*)d_in[1];
  const float* bq = (const float*)d_in[2];
  const float* Wk = (const float*)d_in[3];
  const float* bk = (const float*)d_in[4];
  const float* Wv = (const float*)d_in[5];
  const float* bv = (const float*)d_in[6];
  const float* Wp = (const float*)d_in[7];
  const float* bp = (const float*)d_in[8];
  float* out = (float*)d_out;                        // fp32 output

  const size_t PER_B = 256 * 6 * 512;       // 786432 elems per tensor per batch
  const size_t WSEG  = 4 * 262144;          // converted weights: Wq,Wk,Wv,Wp

  int NB = 16;
  while (NB > 1 && (WSEG + (size_t)5 * NB * PER_B) * 2 > ws_size) NB >>= 1;

  u16* wbf = (u16*)d_ws;
  u16* Wqb = wbf;
  u16* Wkb = wbf + 262144;
  u16* Wvb = wbf + 2 * 262144;
  u16* Wpb = wbf + 3 * 262144;

  const size_t slab = (size_t)NB * PER_B;
  u16* xbf  = wbf + WSEG;
  u16* q_ws = xbf + slab;
  u16* k_ws = q_ws + slab;
  u16* v_ws = k_ws + slab;
  u16* y_ws = v_ws + slab;

  cvt_w<<<dim3(256, 4), 256, 0, stream>>>(Wq, Wk, Wv, Wp, wbf);

  const int nslab = 16 / NB;
  for (int s = 0; s < nslab; ++s) {
    const float* x_s  = x   + (size_t)s * NB * PER_B;
    float*      out_s = out + (size_t)s * NB * PER_B;
    cvt_x<<<dim3(NB * 768), 256, 0, stream>>>(x_s, xbf);
    gemm_bt<<<dim3(NB * 12, 4, 3), 256, 0, stream>>>(
        xbf, Wqb, Wkb, Wvb, bq, bk, bv, q_ws, k_ws, v_ws, nullptr, 1);
    attn<<<dim3(NB * 48), 512, 0, stream>>>(q_ws, k_ws, v_ws, y_ws);
    gemm_bt<<<dim3(NB * 12, 4, 1), 256, 0, stream>>>(
        y_ws, Wpb, Wpb, Wpb, bp, bp, bp, nullptr, nullptr, nullptr, out_s, 0);
  }
}